// Round 16
// baseline (996.358 us; speedup 1.0000x reference)
//
#include <hip/hip_runtime.h>
#include <stdint.h>

#define DIM 384
#define WIN 64
#define HEADS 12
#define HD 32
#define NWIN 4096

typedef _Float16 f16;
typedef unsigned int u32;
typedef _Float16 half8 __attribute__((ext_vector_type(8)));
typedef _Float16 half4 __attribute__((ext_vector_type(4)));
typedef float floatx4 __attribute__((ext_vector_type(4)));

#define AS1 __attribute__((address_space(1)))
#define AS3 __attribute__((address_space(3)))

__device__ __forceinline__ void gl_lds16(const void* g, void* l) {
    __builtin_amdgcn_global_load_lds((const AS1 u32*)g, (AS3 u32*)l, 16, 0, 0);
}

// ---------------- fp32 -> fp16 convert (proj weights) ----------------
__global__ void cvt_kernel(const float* __restrict__ in, f16* __restrict__ out, long n4) {
    long i = (long)blockIdx.x * blockDim.x + threadIdx.x;
    const long stride = (long)gridDim.x * blockDim.x;
    for (; i < n4; i += stride) {
        float4 v = ((const float4*)in)[i];
        half4 h;
        h[0] = (f16)v.x; h[1] = (f16)v.y; h[2] = (f16)v.z; h[3] = (f16)v.w;
        ((half4*)out)[i] = h;
    }
}

// ---------------- pack qkv_w fp32[1152][384] -> Bp[colb 6][s 12][kc 4][u 192][8] f16
__global__ void pack_w_kernel(const float* __restrict__ w, f16* __restrict__ Bp) {
    const int t = blockIdx.x * 256 + threadIdx.x;      // 55296 chunks
    const int colb = t / 9216;
    const int r1 = t % 9216;
    const int s = r1 / 768;
    const int r2 = r1 % 768;
    const int kc = r2 / 192, u = r2 % 192;
    const float* sp = w + (size_t)(colb * 192 + u) * DIM + s * 32 + kc * 8;
    float4 a = *(const float4*)sp;
    float4 b = *(const float4*)(sp + 4);
    half8 o;
    o[0] = (f16)a.x; o[1] = (f16)a.y; o[2] = (f16)a.z; o[3] = (f16)a.w;
    o[4] = (f16)b.x; o[5] = (f16)b.y; o[6] = (f16)b.z; o[7] = (f16)b.w;
    *(half8*)(Bp + (size_t)t * 8) = o;
}

// ---------------- QKV GEMM: 128x192 block, BK=32, 4 waves (wave tile 64x96, acc 4x6)
// A: fp32 x -> reg (4x float4) -> f16 XOR-swizzled LDS dbuf (in-kernel cvt).
//    row=i>>3 staging map: wave's 8 rows span all 4 XOR classes -> balanced banks.
// B: packed panels via 2-buf global_load_lds (3/thr).
// 40 KB LDS + (256,3) reg cap -> 3-4 blocks/CU (12-16 waves): latency-hiding TLP.
// Ledger: head vmcnt(4) drains B(t) keeps A(t+1); writeA(t+1) implicit wait on
// A-loads (oldest) keeps B(t+1) in flight across the barrier.
__global__ void __launch_bounds__(256, 3)
qkv_kernel(const float* __restrict__ X32, const f16* __restrict__ Bp,
           f16* __restrict__ q_arr, f16* __restrict__ k_arr,
           f16* __restrict__ v_int, int nwg)
{
    __shared__ __align__(16) f16 xa[2][128][32];   // 16 KB : A f16 [buf][row][32] XOR
    __shared__ __align__(16) f16 ldsB[2][6144];    // 24 KB : [buf][kc4][u192][8]

    int lin = blockIdx.x;
    int nlin = lin;
    if ((nwg & 7) == 0) nlin = (lin & 7) * (nwg >> 3) + (lin >> 3);
    const int colb = nlin % 6, rowb = nlin / 6;
    const int row0 = rowb * 128;

    const int tid = threadIdx.x;
    const int wave = tid >> 6, lane = tid & 63;
    const int g = lane >> 4, c = lane & 15;
    const int wm = wave >> 1, wn = wave & 1;       // 2 x 2 wave grid

    floatx4 acc[4][6] = {};
    float4 rA[4];

    auto loadA = [&](int t) {                      // 128 rows x 32 k fp32 -> 4 float4/thr
#pragma unroll
        for (int r = 0; r < 4; ++r) {
            const int i = r * 256 + tid;           // 0..1023
            const int row = i >> 3, kq = i & 7;
            rA[r] = *(const float4*)(X32 + (size_t)(row0 + row) * DIM + t * 32 + kq * 4);
        }
    };
    auto writeA = [&](int t) {
#pragma unroll
        for (int r = 0; r < 4; ++r) {
            const int i = r * 256 + tid;
            const int row = i >> 3, kq = i & 7;
            const int sl = (kq >> 1) ^ ((row >> 1) & 3);
            half4 h;
            h[0] = (f16)rA[r].x; h[1] = (f16)rA[r].y;
            h[2] = (f16)rA[r].z; h[3] = (f16)rA[r].w;
            *(half4*)&xa[t & 1][row][sl * 8 + (kq & 1) * 4] = h;
        }
    };
    auto stageB = [&](int t) {                     // 12 KB: u 192 x k 32, 3 gl_lds/thr
        f16* db = &ldsB[t & 1][0];
#pragma unroll
        for (int r = 0; r < 3; ++r) {
            const int ch = r * 256 + tid;          // 0..767 (16B chunks)
            gl_lds16(Bp + ((size_t)colb * 12 + t) * 6144 + (size_t)ch * 8, db + ch * 8);
        }
    };

    // prologue: queue = [A(0)4, B(0)3]; writeA(0) waits A(0) (vmcnt<=3), keeps B(0)
    loadA(0); stageB(0);
    writeA(0);
    loadA(1);                                      // queue [B(0)3, A(1)4]

#pragma unroll
    for (int t = 0; t < 12; ++t) {
        // head outstanding (steady): [B(t)3, A(t+1)4] -> vmcnt(4) drains B(t)
        if (t < 11) asm volatile("s_waitcnt vmcnt(4)" ::: "memory");
        else        asm volatile("s_waitcnt vmcnt(0)" ::: "memory");
        asm volatile("s_waitcnt lgkmcnt(0)" ::: "memory");
        __builtin_amdgcn_sched_barrier(0);
        __builtin_amdgcn_s_barrier();
        __builtin_amdgcn_sched_barrier(0);
        if (t < 11) stageB(t + 1);                 // writes ldsB[(t+1)&1]; readers done

        half8 af[4], bf[6];
#pragma unroll
        for (int mi = 0; mi < 4; ++mi) {
            const int row = wm * 64 + mi * 16 + c;
            const int sl = g ^ ((row >> 1) & 3);
            af[mi] = *(const half8*)&xa[t & 1][row][sl * 8];
        }
#pragma unroll
        for (int ni = 0; ni < 6; ++ni) {
            const int u = wn * 96 + ni * 16 + c;
            bf[ni] = *(const half8*)&ldsB[t & 1][g * 1536 + u * 8];
        }
#pragma unroll
        for (int mi = 0; mi < 4; ++mi)
#pragma unroll
            for (int ni = 0; ni < 6; ++ni)
                acc[mi][ni] = __builtin_amdgcn_mfma_f32_16x16x32_f16(
                    af[mi], bf[ni], acc[mi][ni], 0, 0, 0);

        // writeA(t+1): waits A(t+1) (oldest, vmcnt<=3) -> B(t+1) stays in flight
        if (t < 11) writeA(t + 1);
        if (t < 10) loadA(t + 2);                  // queue [B(t+1)3, A(t+2)4]
    }

    // epilogue: scatter q/k row-major per (b,h), v interleaved for attn B-frags
    const int which = colb >> 1;           // 0=q 1=k 2=v
    const int dbase = (colb & 1) * 192;
    const int b0 = rowb * 2 + wm;          // BM=128 = 2 windows; wave-row wm owns one
    if (which < 2) {
        f16* dst = which ? k_arr : q_arr;
        const float sc = which ? 1.0f : 0.17677669529663687f;  // 32^-0.5 folded into q
#pragma unroll
        for (int ni = 0; ni < 6; ++ni) {
            const int d = dbase + wn * 96 + ni * 16 + c;
            const int h = d >> 5, e = d & 31;
            f16* base = dst + (size_t)(b0 * HEADS + h) * (WIN * HD) + e;
#pragma unroll
            for (int mi = 0; mi < 4; ++mi)
#pragma unroll
                for (int j = 0; j < 4; ++j) {
                    const int n = mi * 16 + g * 4 + j;
                    base[(size_t)n * HD] = (f16)(acc[mi][ni][j] * sc);
                }
        }
    } else {
#pragma unroll
        for (int ni = 0; ni < 6; ++ni) {
            const int d = dbase + wn * 96 + ni * 16 + c;
            const int h = d >> 5, e = d & 31;
            f16* vb = v_int + (size_t)(b0 * HEADS + h) * (WIN * HD);
#pragma unroll
            for (int mi = 0; mi < 4; ++mi) {
                const int n0 = mi * 16 + g * 4;
                half4 pk;
#pragma unroll
                for (int j = 0; j < 4; ++j) pk[j] = (f16)acc[mi][ni][j];
                *(half4*)(vb + (n0 >> 3) * 256 + e * 8 + (n0 & 7)) = pk;
            }
        }
    }
}

// ---------------- proj GEMM: out = A[M][384](f16) * Bw[384][384]^T + bias (fp32 out)
__global__ void proj_kernel(const f16* __restrict__ A, const f16* __restrict__ Bw,
                            float* __restrict__ outp, const float* __restrict__ proj_b,
                            int nwg)
{
    __shared__ __align__(16) f16 lds[3][2][4][128][8];   // 48 KB

    int lin = blockIdx.x;
    int nlin = lin;
    if ((nwg & 7) == 0) nlin = (lin & 7) * (nwg >> 3) + (lin >> 3);
    const int colb = nlin % 3, rowb = nlin / 3;
    const int col0 = colb * 128, row0 = rowb * 128;

    const int tid = threadIdx.x;
    const int wave = tid >> 6, lane = tid & 63;
    const int g = lane >> 4, c = lane & 15;
    const int wm = wave >> 1, wn = wave & 1;

    floatx4 acc[4][4] = {};

    auto stage = [&](int t) {
        const int k0 = t * 32;
#pragma unroll
        for (int r = 0; r < 4; ++r) {
            const int u = wave + r * 4;       // 0..15
            const int isB = u >> 3;
            const int uu = u & 7;
            const int kc = uu >> 1, m0 = (uu & 1) * 64;
            const f16* src = (isB ? Bw + (size_t)(col0 + m0 + lane) * DIM
                                  : A  + (size_t)(row0 + m0 + lane) * DIM)
                             + k0 + kc * 8;
            gl_lds16(src, &lds[t % 3][isB][kc][m0][0]);
        }
    };

    stage(0); stage(1);

#pragma unroll
    for (int s = 0; s < 12; ++s) {
        if (s < 11) asm volatile("s_waitcnt vmcnt(4)" ::: "memory");
        else        asm volatile("s_waitcnt vmcnt(0)" ::: "memory");
        asm volatile("s_waitcnt lgkmcnt(0)" ::: "memory");
        __builtin_amdgcn_sched_barrier(0);
        __builtin_amdgcn_s_barrier();
        __builtin_amdgcn_sched_barrier(0);
        if (s < 10) stage(s + 2);

        half8 af[4], bf[4];
#pragma unroll
        for (int i = 0; i < 4; ++i) {
            af[i] = *(const half8*)&lds[s % 3][0][g][wm * 64 + i * 16 + c][0];
            bf[i] = *(const half8*)&lds[s % 3][1][g][wn * 64 + i * 16 + c][0];
        }
#pragma unroll
        for (int mi = 0; mi < 4; ++mi)
#pragma unroll
            for (int ni = 0; ni < 4; ++ni)
                acc[mi][ni] = __builtin_amdgcn_mfma_f32_16x16x32_f16(
                    af[mi], bf[ni], acc[mi][ni], 0, 0, 0);
    }

#pragma unroll
    for (int ni = 0; ni < 4; ++ni) {
        const int d = col0 + wn * 64 + ni * 16 + c;
        const float pb = proj_b[d];
#pragma unroll
        for (int mi = 0; mi < 4; ++mi)
#pragma unroll
            for (int j = 0; j < 4; ++j) {
                const size_t trow = (size_t)row0 + wm * 64 + mi * 16 + g * 4 + j;
                outp[trow * DIM + d] = acc[mi][ni][j] + pb;
            }
    }
}

// ---------------- attention: one block per (window, head) ----------------
__global__ void attn_kernel(const f16* __restrict__ q_arr, const f16* __restrict__ k_arr,
                            const f16* __restrict__ v_int,
                            const float* __restrict__ bias_table,
                            f16* __restrict__ attn_out)
{
    const int bid = blockIdx.x;
    const int bw = bid / HEADS, h = bid % HEADS;
    const f16* q = q_arr + (size_t)bid * (WIN * HD);
    const f16* k = k_arr + (size_t)bid * (WIN * HD);
    const f16* v = v_int + (size_t)bid * (WIN * HD);

    const int tid = threadIdx.x;
    const int w = tid >> 6, lane = tid & 63;
    const int g = lane >> 4, c = lane & 15;

    __shared__ float bias_lds[2 * WIN - 1];
    __shared__ __align__(16) f16 p_lds[8][64][8];   // P in A-frag-interleaved layout

    for (int i = tid; i < 2 * WIN - 1; i += 256)
        bias_lds[i] = bias_table[(size_t)i * HEADS + h];
    __syncthreads();

    // S = Q K^T : wave w owns rows 16w..16w+15, all 64 cols
    half8 qa = *(const half8*)(q + (16 * w + c) * HD + g * 8);
    floatx4 s[4];
#pragma unroll
    for (int t = 0; t < 4; ++t) {
        half8 kb = *(const half8*)(k + (16 * t + c) * HD + g * 8);
        floatx4 z = {};
        s[t] = __builtin_amdgcn_mfma_f32_16x16x32_f16(qa, kb, z, 0, 0, 0);
    }

    // bias + row softmax
    float pr[4][4];
#pragma unroll
    for (int j = 0; j < 4; ++j) {
        const int n = 16 * w + g * 4 + j;
        float mx = -1e30f;
#pragma unroll
        for (int t = 0; t < 4; ++t) {
            const int m = 16 * t + c;
            pr[j][t] = s[t][j] + bias_lds[n - m + 63];
            mx = fmaxf(mx, pr[j][t]);
        }
        mx = fmaxf(mx, __shfl_xor(mx, 1));
        mx = fmaxf(mx, __shfl_xor(mx, 2));
        mx = fmaxf(mx, __shfl_xor(mx, 4));
        mx = fmaxf(mx, __shfl_xor(mx, 8));
        float sum = 0.f;
#pragma unroll
        for (int t = 0; t < 4; ++t) { pr[j][t] = __expf(pr[j][t] - mx); sum += pr[j][t]; }
        sum += __shfl_xor(sum, 1);
        sum += __shfl_xor(sum, 2);
        sum += __shfl_xor(sum, 4);
        sum += __shfl_xor(sum, 8);
        const float r = 1.0f / sum;
#pragma unroll
        for (int t = 0; t < 4; ++t) {
            const int m = 16 * t + c;
            p_lds[m >> 3][n][m & 7] = (f16)(pr[j][t] * r);
        }
    }
    __syncthreads();

    // O = P V
    half8 pa0 = *(const half8*)&p_lds[g][16 * w + c][0];
    half8 pa1 = *(const half8*)&p_lds[4 + g][16 * w + c][0];
    floatx4 o[2];
#pragma unroll
    for (int t = 0; t < 2; ++t) {
        half8 vb0 = *(const half8*)(v + g * 256 + (16 * t + c) * 8);
        half8 vb1 = *(const half8*)(v + (4 + g) * 256 + (16 * t + c) * 8);
        floatx4 z = {};
        o[t] = __builtin_amdgcn_mfma_f32_16x16x32_f16(pa0, vb0, z, 0, 0, 0);
        o[t] = __builtin_amdgcn_mfma_f32_16x16x32_f16(pa1, vb1, o[t], 0, 0, 0);
    }
#pragma unroll
    for (int t = 0; t < 2; ++t)
#pragma unroll
        for (int j = 0; j < 4; ++j) {
            const int n = 16 * w + g * 4 + j;
            attn_out[((size_t)bw * WIN + n) * DIM + h * HD + 16 * t + c] = (f16)o[t][j];
        }
}

extern "C" void kernel_launch(void* const* d_in, const int* in_sizes, int n_in,
                              void* d_out, int out_size, void* d_ws, size_t ws_size,
                              hipStream_t stream) {
    const float* x          = (const float*)d_in[0];
    const float* qkv_w      = (const float*)d_in[1];
    const float* proj_w     = (const float*)d_in[2];
    const float* proj_b     = (const float*)d_in[3];
    const float* bias_table = (const float*)d_in[4];
    float* out = (float*)d_out;
    (void)in_sizes; (void)n_in; (void)out_size;

    uintptr_t p = (uintptr_t)d_ws;
    auto carve = [&](size_t bytes) -> void* {
        uintptr_t q = p; p += (bytes + 255) & ~(size_t)255; return (void*)q;
    };
    f16* w16_proj = (f16*)carve((size_t)DIM * DIM * 2);
    f16* Bp       = (f16*)carve((size_t)6 * 12 * 768 * 8 * 2);   // 884736 B
    const size_t fixed = p - (uintptr_t)d_ws;

    // per-window ws: q + k + v + ao = 4 * 49152 B
    int CB = NWIN;
    while (CB > 16 && fixed + (size_t)CB * 196608 + 4096 > ws_size) CB >>= 1;

    f16* qa = (f16*)carve((size_t)CB * HEADS * WIN * HD * 2);
    f16* ka = (f16*)carve((size_t)CB * HEADS * WIN * HD * 2);
    f16* vi = (f16*)carve((size_t)CB * HEADS * WIN * HD * 2);
    f16* ao = (f16*)carve((size_t)CB * WIN * DIM * 2);

    cvt_kernel<<<dim3(64), dim3(256), 0, stream>>>(proj_w, w16_proj, (long)(DIM * DIM / 4));
    pack_w_kernel<<<dim3(216), dim3(256), 0, stream>>>(qkv_w, Bp);

    for (int c0 = 0; c0 < NWIN; c0 += CB) {
        const float* xc = x + (size_t)c0 * WIN * DIM;

        const int nwg1 = (CB * WIN / 128) * 6;          // 128-row blocks x 6 col-panels
        qkv_kernel<<<dim3(nwg1), dim3(256), 0, stream>>>(xc, Bp, qa, ka, vi, nwg1);

        attn_kernel<<<dim3(CB * HEADS), dim3(256), 0, stream>>>(qa, ka, vi, bias_table, ao);

        const int nwg2 = (CB * WIN / 128) * 3;
        proj_kernel<<<dim3(nwg2), dim3(256), 0, stream>>>(ao, w16_proj,
                                                          out + (size_t)c0 * WIN * DIM, proj_b, nwg2);
    }
}

// Round 17
// 831.996 us; speedup vs baseline: 1.1976x; 1.1976x over previous
//
#include <hip/hip_runtime.h>
#include <stdint.h>

#define DIM 384
#define WIN 64
#define HEADS 12
#define HD 32
#define NWIN 4096

typedef _Float16 f16;
typedef unsigned int u32;
typedef _Float16 half8 __attribute__((ext_vector_type(8)));
typedef _Float16 half4 __attribute__((ext_vector_type(4)));
typedef float floatx4 __attribute__((ext_vector_type(4)));

#define AS1 __attribute__((address_space(1)))
#define AS3 __attribute__((address_space(3)))

__device__ __forceinline__ void gl_lds16(const void* g, void* l) {
    __builtin_amdgcn_global_load_lds((const AS1 u32*)g, (AS3 u32*)l, 16, 0, 0);
}

// ---------------- fp32 -> fp16 convert (proj weights) ----------------
__global__ void cvt_kernel(const float* __restrict__ in, f16* __restrict__ out, long n4) {
    long i = (long)blockIdx.x * blockDim.x + threadIdx.x;
    const long stride = (long)gridDim.x * blockDim.x;
    for (; i < n4; i += stride) {
        float4 v = ((const float4*)in)[i];
        half4 h;
        h[0] = (f16)v.x; h[1] = (f16)v.y; h[2] = (f16)v.z; h[3] = (f16)v.w;
        ((half4*)out)[i] = h;
    }
}

// ---------------- pack qkv_w fp32[1152][384] -> Bp[colb 6][s 12][kc 4][u 192][8] f16
__global__ void pack_w_kernel(const float* __restrict__ w, f16* __restrict__ Bp) {
    const int t = blockIdx.x * 256 + threadIdx.x;      // 55296 chunks
    const int colb = t / 9216;
    const int r1 = t % 9216;
    const int s = r1 / 768;
    const int r2 = r1 % 768;
    const int kc = r2 / 192, u = r2 % 192;
    const float* sp = w + (size_t)(colb * 192 + u) * DIM + s * 32 + kc * 8;
    float4 a = *(const float4*)sp;
    float4 b = *(const float4*)(sp + 4);
    half8 o;
    o[0] = (f16)a.x; o[1] = (f16)a.y; o[2] = (f16)a.z; o[3] = (f16)a.w;
    o[4] = (f16)b.x; o[5] = (f16)b.y; o[6] = (f16)b.z; o[7] = (f16)b.w;
    *(half8*)(Bp + (size_t)t * 8) = o;
}

// ---------------- QKV GEMM: 128x192 block, BK=64, 4 waves (wave tile 64x96, acc 4x6)
// A: fp32 x -> reg (8x float4) -> f16 XOR-swizzled LDS dbuf (in-kernel cvt).
// B: packed panels via 2-buf global_load_lds.
// 80 KB LDS -> 2 blocks/CU: two independent barrier domains overlap (m114).
// Queue ledger: head vmcnt(8) drains B(t), keeps A(t+1); writeA(t+1) implicitly
// waits A(t+1) (vmcnt(6)), draining nothing younger; B(t+1) spans the barrier.
__global__ void __launch_bounds__(256, 2)
qkv_kernel(const float* __restrict__ X32, const f16* __restrict__ Bp,
           f16* __restrict__ q_arr, f16* __restrict__ k_arr,
           f16* __restrict__ v_int, int nwg)
{
    __shared__ __align__(16) f16 xa[2][2][128][32];   // 32 KB : A f16 [buf][ks][row][32] XOR
    __shared__ __align__(16) f16 ldsB[2][12288];      // 48 KB : [buf][ss2][kc4][u192][8]

    int lin = blockIdx.x;
    int nlin = lin;
    if ((nwg & 7) == 0) nlin = (lin & 7) * (nwg >> 3) + (lin >> 3);
    const int colb = nlin % 6, rowb = nlin / 6;
    const int row0 = rowb * 128;

    const int tid = threadIdx.x;
    const int wave = tid >> 6, lane = tid & 63;
    const int g = lane >> 4, c = lane & 15;
    const int wm = wave >> 1, wn = wave & 1;       // 2 x 2 wave grid

    floatx4 acc[4][6] = {};
    float4 rA[8];

    auto loadA = [&](int t) {                      // 128 rows x 64 k fp32 -> 8 float4/thr
#pragma unroll
        for (int r = 0; r < 8; ++r) {
            const int i = r * 256 + tid;           // 0..2047
            const int row = i >> 4, kq = i & 15;
            rA[r] = *(const float4*)(X32 + (size_t)(row0 + row) * DIM + t * 64 + kq * 4);
        }
    };
    auto writeA = [&](int t) {
#pragma unroll
        for (int r = 0; r < 8; ++r) {
            const int i = r * 256 + tid;
            const int row = i >> 4, kq = i & 15;
            const int ks = kq >> 3, kq2 = kq & 7;
            const int sl = (kq2 >> 1) ^ ((row >> 1) & 3);
            half4 h;
            h[0] = (f16)rA[r].x; h[1] = (f16)rA[r].y;
            h[2] = (f16)rA[r].z; h[3] = (f16)rA[r].w;
            *(half4*)&xa[t & 1][ks][row][sl * 8 + (kq2 & 1) * 4] = h;
        }
    };
    auto stageB = [&](int t) {                     // 24 KB: u 192 x k 64, 6 gl_lds/thr
        f16* db = &ldsB[t & 1][0];
#pragma unroll
        for (int r = 0; r < 6; ++r) {
            const int ch = r * 256 + tid;          // 0..1535
            const int ss = ch / 768, rem = ch % 768;
            const f16* src = Bp + ((size_t)colb * 12 + (2 * t + ss)) * 6144 + (size_t)rem * 8;
            gl_lds16(src, db + ch * 8);
        }
    };

    // prologue: queue = [A(0)8, B(0)6]; writeA(0) waits A(0), B(0) stays in flight
    loadA(0); stageB(0);
    writeA(0);
    loadA(1);

#pragma unroll
    for (int t = 0; t < 6; ++t) {
        // head outstanding (steady): [B(t)6, A(t+1)8] -> vmcnt(8) drains B(t)
        if (t < 5) asm volatile("s_waitcnt vmcnt(8)" ::: "memory");
        else       asm volatile("s_waitcnt vmcnt(0)" ::: "memory");
        asm volatile("s_waitcnt lgkmcnt(0)" ::: "memory");
        __builtin_amdgcn_sched_barrier(0);
        __builtin_amdgcn_s_barrier();
        __builtin_amdgcn_sched_barrier(0);
        if (t < 5) stageB(t + 1);                  // writes ldsB[(t+1)&1]; readers done

        const f16* bb = &ldsB[t & 1][0];
#pragma unroll
        for (int ks = 0; ks < 2; ++ks) {
            half8 af[4], bf[6];
#pragma unroll
            for (int mi = 0; mi < 4; ++mi) {
                const int row = wm * 64 + mi * 16 + c;
                const int sl = g ^ ((row >> 1) & 3);
                af[mi] = *(const half8*)&xa[t & 1][ks][row][sl * 8];
            }
#pragma unroll
            for (int ni = 0; ni < 6; ++ni) {
                const int u = wn * 96 + ni * 16 + c;
                bf[ni] = *(const half8*)(bb + ks * 6144 + g * 1536 + u * 8);
            }
#pragma unroll
            for (int mi = 0; mi < 4; ++mi)
#pragma unroll
                for (int ni = 0; ni < 6; ++ni)
                    acc[mi][ni] = __builtin_amdgcn_mfma_f32_16x16x32_f16(
                        af[mi], bf[ni], acc[mi][ni], 0, 0, 0);
        }
        // writeA(t+1): waits A(t+1) (vmcnt(6)); xa[(t+1)&1] readers passed head barrier
        if (t < 5) writeA(t + 1);
        if (t < 4) loadA(t + 2);
    }

    // epilogue: scatter q/k row-major per (b,h), v interleaved for attn B-frags
    const int which = colb >> 1;           // 0=q 1=k 2=v
    const int dbase = (colb & 1) * 192;
    const int b0 = rowb * 2 + wm;          // BM=128 = 2 windows; wave-row wm owns one
    if (which < 2) {
        f16* dst = which ? k_arr : q_arr;
        const float sc = which ? 1.0f : 0.17677669529663687f;  // 32^-0.5 folded into q
#pragma unroll
        for (int ni = 0; ni < 6; ++ni) {
            const int d = dbase + wn * 96 + ni * 16 + c;
            const int h = d >> 5, e = d & 31;
            f16* base = dst + (size_t)(b0 * HEADS + h) * (WIN * HD) + e;
#pragma unroll
            for (int mi = 0; mi < 4; ++mi)
#pragma unroll
                for (int j = 0; j < 4; ++j) {
                    const int n = mi * 16 + g * 4 + j;
                    base[(size_t)n * HD] = (f16)(acc[mi][ni][j] * sc);
                }
        }
    } else {
#pragma unroll
        for (int ni = 0; ni < 6; ++ni) {
            const int d = dbase + wn * 96 + ni * 16 + c;
            const int h = d >> 5, e = d & 31;
            f16* vb = v_int + (size_t)(b0 * HEADS + h) * (WIN * HD);
#pragma unroll
            for (int mi = 0; mi < 4; ++mi) {
                const int n0 = mi * 16 + g * 4;
                half4 pk;
#pragma unroll
                for (int j = 0; j < 4; ++j) pk[j] = (f16)acc[mi][ni][j];
                *(half4*)(vb + (n0 >> 3) * 256 + e * 8 + (n0 & 7)) = pk;
            }
        }
    }
}

// ---------------- proj GEMM: out = A[M][384](f16) * Bw[384][384]^T + bias (fp32 out)
__global__ void proj_kernel(const f16* __restrict__ A, const f16* __restrict__ Bw,
                            float* __restrict__ outp, const float* __restrict__ proj_b,
                            int nwg)
{
    __shared__ __align__(16) f16 lds[3][2][4][128][8];   // 48 KB

    int lin = blockIdx.x;
    int nlin = lin;
    if ((nwg & 7) == 0) nlin = (lin & 7) * (nwg >> 3) + (lin >> 3);
    const int colb = nlin % 3, rowb = nlin / 3;
    const int col0 = colb * 128, row0 = rowb * 128;

    const int tid = threadIdx.x;
    const int wave = tid >> 6, lane = tid & 63;
    const int g = lane >> 4, c = lane & 15;
    const int wm = wave >> 1, wn = wave & 1;

    floatx4 acc[4][4] = {};

    auto stage = [&](int t) {
        const int k0 = t * 32;
#pragma unroll
        for (int r = 0; r < 4; ++r) {
            const int u = wave + r * 4;       // 0..15
            const int isB = u >> 3;
            const int uu = u & 7;
            const int kc = uu >> 1, m0 = (uu & 1) * 64;
            const f16* src = (isB ? Bw + (size_t)(col0 + m0 + lane) * DIM
                                  : A  + (size_t)(row0 + m0 + lane) * DIM)
                             + k0 + kc * 8;
            gl_lds16(src, &lds[t % 3][isB][kc][m0][0]);
        }
    };

    stage(0); stage(1);

#pragma unroll
    for (int s = 0; s < 12; ++s) {
        if (s < 11) asm volatile("s_waitcnt vmcnt(4)" ::: "memory");
        else        asm volatile("s_waitcnt vmcnt(0)" ::: "memory");
        asm volatile("s_waitcnt lgkmcnt(0)" ::: "memory");
        __builtin_amdgcn_sched_barrier(0);
        __builtin_amdgcn_s_barrier();
        __builtin_amdgcn_sched_barrier(0);
        if (s < 10) stage(s + 2);

        half8 af[4], bf[4];
#pragma unroll
        for (int i = 0; i < 4; ++i) {
            af[i] = *(const half8*)&lds[s % 3][0][g][wm * 64 + i * 16 + c][0];
            bf[i] = *(const half8*)&lds[s % 3][1][g][wn * 64 + i * 16 + c][0];
        }
#pragma unroll
        for (int mi = 0; mi < 4; ++mi)
#pragma unroll
            for (int ni = 0; ni < 4; ++ni)
                acc[mi][ni] = __builtin_amdgcn_mfma_f32_16x16x32_f16(
                    af[mi], bf[ni], acc[mi][ni], 0, 0, 0);
    }

#pragma unroll
    for (int ni = 0; ni < 4; ++ni) {
        const int d = col0 + wn * 64 + ni * 16 + c;
        const float pb = proj_b[d];
#pragma unroll
        for (int mi = 0; mi < 4; ++mi)
#pragma unroll
            for (int j = 0; j < 4; ++j) {
                const size_t trow = (size_t)row0 + wm * 64 + mi * 16 + g * 4 + j;
                outp[trow * DIM + d] = acc[mi][ni][j] + pb;
            }
    }
}

// ---------------- attention: one block per (window, head) ----------------
__global__ void attn_kernel(const f16* __restrict__ q_arr, const f16* __restrict__ k_arr,
                            const f16* __restrict__ v_int,
                            const float* __restrict__ bias_table,
                            f16* __restrict__ attn_out)
{
    const int bid = blockIdx.x;
    const int bw = bid / HEADS, h = bid % HEADS;
    const f16* q = q_arr + (size_t)bid * (WIN * HD);
    const f16* k = k_arr + (size_t)bid * (WIN * HD);
    const f16* v = v_int + (size_t)bid * (WIN * HD);

    const int tid = threadIdx.x;
    const int w = tid >> 6, lane = tid & 63;
    const int g = lane >> 4, c = lane & 15;

    __shared__ float bias_lds[2 * WIN - 1];
    __shared__ __align__(16) f16 p_lds[8][64][8];   // P in A-frag-interleaved layout

    for (int i = tid; i < 2 * WIN - 1; i += 256)
        bias_lds[i] = bias_table[(size_t)i * HEADS + h];
    __syncthreads();

    // S = Q K^T : wave w owns rows 16w..16w+15, all 64 cols
    half8 qa = *(const half8*)(q + (16 * w + c) * HD + g * 8);
    floatx4 s[4];
#pragma unroll
    for (int t = 0; t < 4; ++t) {
        half8 kb = *(const half8*)(k + (16 * t + c) * HD + g * 8);
        floatx4 z = {};
        s[t] = __builtin_amdgcn_mfma_f32_16x16x32_f16(qa, kb, z, 0, 0, 0);
    }

    // bias + row softmax
    float pr[4][4];
#pragma unroll
    for (int j = 0; j < 4; ++j) {
        const int n = 16 * w + g * 4 + j;
        float mx = -1e30f;
#pragma unroll
        for (int t = 0; t < 4; ++t) {
            const int m = 16 * t + c;
            pr[j][t] = s[t][j] + bias_lds[n - m + 63];
            mx = fmaxf(mx, pr[j][t]);
        }
        mx = fmaxf(mx, __shfl_xor(mx, 1));
        mx = fmaxf(mx, __shfl_xor(mx, 2));
        mx = fmaxf(mx, __shfl_xor(mx, 4));
        mx = fmaxf(mx, __shfl_xor(mx, 8));
        float sum = 0.f;
#pragma unroll
        for (int t = 0; t < 4; ++t) { pr[j][t] = __expf(pr[j][t] - mx); sum += pr[j][t]; }
        sum += __shfl_xor(sum, 1);
        sum += __shfl_xor(sum, 2);
        sum += __shfl_xor(sum, 4);
        sum += __shfl_xor(sum, 8);
        const float r = 1.0f / sum;
#pragma unroll
        for (int t = 0; t < 4; ++t) {
            const int m = 16 * t + c;
            p_lds[m >> 3][n][m & 7] = (f16)(pr[j][t] * r);
        }
    }
    __syncthreads();

    // O = P V
    half8 pa0 = *(const half8*)&p_lds[g][16 * w + c][0];
    half8 pa1 = *(const half8*)&p_lds[4 + g][16 * w + c][0];
    floatx4 o[2];
#pragma unroll
    for (int t = 0; t < 2; ++t) {
        half8 vb0 = *(const half8*)(v + g * 256 + (16 * t + c) * 8);
        half8 vb1 = *(const half8*)(v + (4 + g) * 256 + (16 * t + c) * 8);
        floatx4 z = {};
        o[t] = __builtin_amdgcn_mfma_f32_16x16x32_f16(pa0, vb0, z, 0, 0, 0);
        o[t] = __builtin_amdgcn_mfma_f32_16x16x32_f16(pa1, vb1, o[t], 0, 0, 0);
    }
#pragma unroll
    for (int t = 0; t < 2; ++t)
#pragma unroll
        for (int j = 0; j < 4; ++j) {
            const int n = 16 * w + g * 4 + j;
            attn_out[((size_t)bw * WIN + n) * DIM + h * HD + 16 * t + c] = (f16)o[t][j];
        }
}

extern "C" void kernel_launch(void* const* d_in, const int* in_sizes, int n_in,
                              void* d_out, int out_size, void* d_ws, size_t ws_size,
                              hipStream_t stream) {
    const float* x          = (const float*)d_in[0];
    const float* qkv_w      = (const float*)d_in[1];
    const float* proj_w     = (const float*)d_in[2];
    const float* proj_b     = (const float*)d_in[3];
    const float* bias_table = (const float*)d_in[4];
    float* out = (float*)d_out;
    (void)in_sizes; (void)n_in; (void)out_size;

    uintptr_t p = (uintptr_t)d_ws;
    auto carve = [&](size_t bytes) -> void* {
        uintptr_t q = p; p += (bytes + 255) & ~(size_t)255; return (void*)q;
    };
    f16* w16_proj = (f16*)carve((size_t)DIM * DIM * 2);
    f16* Bp       = (f16*)carve((size_t)6 * 12 * 768 * 8 * 2);   // 884736 B
    const size_t fixed = p - (uintptr_t)d_ws;

    // per-window ws: q + k + v + ao = 4 * 49152 B
    int CB = NWIN;
    while (CB > 16 && fixed + (size_t)CB * 196608 + 4096 > ws_size) CB >>= 1;

    f16* qa = (f16*)carve((size_t)CB * HEADS * WIN * HD * 2);
    f16* ka = (f16*)carve((size_t)CB * HEADS * WIN * HD * 2);
    f16* vi = (f16*)carve((size_t)CB * HEADS * WIN * HD * 2);
    f16* ao = (f16*)carve((size_t)CB * WIN * DIM * 2);

    cvt_kernel<<<dim3(64), dim3(256), 0, stream>>>(proj_w, w16_proj, (long)(DIM * DIM / 4));
    pack_w_kernel<<<dim3(216), dim3(256), 0, stream>>>(qkv_w, Bp);

    for (int c0 = 0; c0 < NWIN; c0 += CB) {
        const float* xc = x + (size_t)c0 * WIN * DIM;

        const int nwg1 = (CB * WIN / 128) * 6;          // 128-row blocks x 6 col-panels
        qkv_kernel<<<dim3(nwg1), dim3(256), 0, stream>>>(xc, Bp, qa, ka, vi, nwg1);

        attn_kernel<<<dim3(CB * HEADS), dim3(256), 0, stream>>>(qa, ka, vi, bias_table, ao);

        const int nwg2 = (CB * WIN / 128) * 3;
        proj_kernel<<<dim3(nwg2), dim3(256), 0, stream>>>(ao, w16_proj,
                                                          out + (size_t)c0 * WIN * DIM, proj_b, nwg2);
    }
}